// Round 5
// baseline (273.348 us; speedup 1.0000x reference)
//
#include <hip/hip_runtime.h>
#include <math.h>

#define GAMMA 0.1f
#define TAU   0.01f
#define NN    256
#define MM    512
#define KK    512

typedef float vf4 __attribute__((ext_vector_type(4)));

__device__ __forceinline__ float sigmoidf(float v) {
    return 1.0f / (1.0f + __expf(-v));
}
__device__ __forceinline__ float4 sigmoid4(float4 v) {
    return make_float4(sigmoidf(v.x), sigmoidf(v.y), sigmoidf(v.z), sigmoidf(v.w));
}
__device__ __forceinline__ float dot4(float4 a, float4 b) {
    return a.x * b.x + a.y * b.y + a.z * b.z + a.w * b.w;
}
__device__ __forceinline__ float4 ntload4(const float4* p) {
    vf4 v = __builtin_nontemporal_load((const vf4*)p);
    return make_float4(v.x, v.y, v.z, v.w);
}

// ---------------------------------------------------------------------------
// Kernel 1: x_new rows (blocks 0..15), psi_z = tanh(z) (blocks 16..17).
// ws[0:256] = phi_xn, ws[256:768] = psi_z.
// ---------------------------------------------------------------------------
__global__ __launch_bounds__(256) void k_state(
    const float* __restrict__ I, const float* __restrict__ x,
    const float* __restrict__ W, const float* __restrict__ z,
    const float* __restrict__ Win1,
    float* __restrict__ out, float* __restrict__ ws)
{
    const int b = blockIdx.x, t = threadIdx.x;
    if (b < 16) {
        const int wave = t >> 6, lane = t & 63;
        const int row0 = b * 16 + wave * 4;
        float4 xv = ((const float4*)x)[lane];
        float4 i0 = ((const float4*)I)[lane];
        float4 i1 = ((const float4*)I)[64 + lane];
        const float4* Wr = (const float4*)(W + row0 * NN);
        float4 w0 = Wr[lane], w1 = Wr[lane + 64], w2 = Wr[lane + 128], w3 = Wr[lane + 192];
        const float4* A = (const float4*)(Win1 + row0 * KK);
        float4 a0 = A[lane],       c0 = A[lane + 64];
        float4 a1 = A[lane + 128], c1 = A[lane + 192];
        float4 a2 = A[lane + 256], c2 = A[lane + 320];
        float4 a3 = A[lane + 384], c3 = A[lane + 448];
        float4 xo = ((const float4*)x)[row0 >> 2];

        float4 ph = sigmoid4(xv);
        float s0 = GAMMA * dot4(w0, ph) + dot4(a0, i0) + dot4(c0, i1);
        float s1 = GAMMA * dot4(w1, ph) + dot4(a1, i0) + dot4(c1, i1);
        float s2 = GAMMA * dot4(w2, ph) + dot4(a2, i0) + dot4(c2, i1);
        float s3 = GAMMA * dot4(w3, ph) + dot4(a3, i0) + dot4(c3, i1);
#pragma unroll
        for (int m = 32; m; m >>= 1) {
            s0 += __shfl_xor(s0, m, 64);
            s1 += __shfl_xor(s1, m, 64);
            s2 += __shfl_xor(s2, m, 64);
            s3 += __shfl_xor(s3, m, 64);
        }
        if (lane == 0) {
            float4 xn;
            xn.x = (1.0f - GAMMA) * xo.x + s0;
            xn.y = (1.0f - GAMMA) * xo.y + s1;
            xn.z = (1.0f - GAMMA) * xo.z + s2;
            xn.w = (1.0f - GAMMA) * xo.w + s3;
            ((float4*)out)[row0 >> 2] = xn;
            ((float4*)ws)[row0 >> 2] = sigmoid4(xn);
        }
    } else {
        const int idx = (b - 16) * 256 + t;
        ws[NN + idx] = tanhf(z[idx]);
    }
}

// ---------------------------------------------------------------------------
// k_WZ (fused, uniform work): 1024 blocks x 512 threads. Every block streams
// exactly 256 KB; every wave exactly 32 KB.
//   even b -> H phase: z_new row (b>>1). 512 thr, 32 f4/thread.
//   odd  b -> D phase: 128 W_new rows, each of 8 waves handles 16 rows.
// ws: [0:256]=phi_xn, [256:768]=psi_z.
// ---------------------------------------------------------------------------
__global__ __launch_bounds__(512, 2) void k_WZ(
    const float* __restrict__ W, const float* __restrict__ Cv,
    const float* __restrict__ D, const float* __restrict__ F,
    const float* __restrict__ H, const float* __restrict__ Win2,
    const float* __restrict__ I, const float* __restrict__ z,
    const float* __restrict__ ws, float* __restrict__ out)
{
    __shared__ float sm[768];   // [0:512)=psi_z, [512:768)=phi_xn
    __shared__ float red[8];
    const int b = blockIdx.x, t = threadIdx.x;
    const int wave = t >> 6, lane = t & 63;

    if (t < 128)      ((float4*)sm)[t] = ((const float4*)(ws + NN))[t];  // psi_z
    else if (t < 192) ((float4*)sm)[t] = ((const float4*)ws)[t - 128];   // phi_xn

    if ((b & 1) == 0) {
        // ================= H phase: one z row, 512 threads =================
        const int row = b >> 1;                            // 0..511
        float wi = Win2[(size_t)row * KK + t] * I[t];
        __syncthreads();
        const float4* H4 = (const float4*)(H + (size_t)row * (NN * NN));
        const float* phi = sm + 512;
        const float4 pj = ((const float4*)phi)[lane];
        float a0 = wi, a1 = 0.0f, a2 = 0.0f, a3 = 0.0f;
        float4 buf[2][8];
#pragma unroll
        for (int u = 0; u < 8; ++u) buf[0][u] = ntload4(&H4[t + 512 * u]);
#pragma unroll
        for (int g = 0; g < 4; ++g) {                      // 4 groups x 8 = 32 f4
            const int cur = g & 1, nxt = cur ^ 1;
            if (g < 3) {
#pragma unroll
                for (int u = 0; u < 8; ++u)
                    buf[nxt][u] = ntload4(&H4[t + 512 * ((g + 1) * 8 + u)]);
            }
#pragma unroll
            for (int u = 0; u < 8; ++u) {
                const float term = phi[wave + 8 * (g * 8 + u)] * dot4(buf[cur][u], pj);
                if      ((u & 3) == 0) a0 += term;
                else if ((u & 3) == 1) a1 += term;
                else if ((u & 3) == 2) a2 += term;
                else                   a3 += term;
            }
        }
        float acc = (a0 + a1) + (a2 + a3);
#pragma unroll
        for (int m = 32; m; m >>= 1) acc += __shfl_xor(acc, m, 64);
        if (lane == 0) red[wave] = acc;
        __syncthreads();
        if (t < 64) {
            float v = (t < 8) ? red[t] : 0.0f;
#pragma unroll
            for (int m = 4; m; m >>= 1) v += __shfl_xor(v, m, 64);
            if (t == 0) {
                const float gt = GAMMA * TAU;
                float zn = (1.0f - gt) * z[row] + gt * (F[row] * ws[NN + row] + v);
                out[NN + NN * NN + row] = zn;
            }
        }
    } else {
        // ================= D phase: 16 rows per wave, 8 waves =================
        const int row0 = (b >> 1) * 128 + wave * 16;       // 0..65520
        const float4* R = (const float4*)(D + (size_t)row0 * MM);  // 128 f4/row
        float wrow = 0.0f, crow = 0.0f;
        if (lane < 16) { wrow = W[row0 + lane]; crow = Cv[row0 + lane]; }
        __syncthreads();
        const float4 z0 = ((const float4*)sm)[lane];
        const float4 z1 = ((const float4*)sm)[64 + lane];

        float p[16];
        float4 A[2][4], B[2][4];
#pragma unroll
        for (int r = 0; r < 4; ++r) {
            A[0][r] = ntload4(&R[lane + 128 * r]);
            B[0][r] = ntload4(&R[lane + 64 + 128 * r]);
        }
#pragma unroll
        for (int g = 0; g < 4; ++g) {
            const int cur = g & 1, nxt = cur ^ 1;
            if (g < 3) {
#pragma unroll
                for (int r = 0; r < 4; ++r) {
                    A[nxt][r] = ntload4(&R[lane + 128 * ((g + 1) * 4 + r)]);
                    B[nxt][r] = ntload4(&R[lane + 64 + 128 * ((g + 1) * 4 + r)]);
                }
            }
#pragma unroll
            for (int r = 0; r < 4; ++r)
                p[g * 4 + r] = dot4(A[cur][r], z0) + dot4(B[cur][r], z1);
        }
        // 16 independent butterflies, interleaved, once per 32 KB stream
#pragma unroll
        for (int m = 32; m; m >>= 1) {
#pragma unroll
            for (int r = 0; r < 16; ++r) p[r] += __shfl_xor(p[r], m, 64);
        }
        float keep = 0.0f;
#pragma unroll
        for (int r = 0; r < 16; ++r) if (lane == r) keep = p[r];
        if (lane < 16) {
            const float phi_i = sm[512 + ((row0 + lane) >> 8)];
            const float phi_j = sm[512 + ((row0 + lane) & 255)];
            float wn = (1.0f - GAMMA) * wrow + GAMMA * (crow * phi_i * phi_j + keep);
            out[NN + row0 + lane] = wn;
        }
    }
}

extern "C" void kernel_launch(void* const* d_in, const int* in_sizes, int n_in,
                              void* d_out, int out_size, void* d_ws, size_t ws_size,
                              hipStream_t stream) {
    const float* I    = (const float*)d_in[0];
    const float* x    = (const float*)d_in[1];
    const float* W    = (const float*)d_in[2];
    const float* z    = (const float*)d_in[3];
    const float* C    = (const float*)d_in[4];
    const float* D    = (const float*)d_in[5];
    const float* F    = (const float*)d_in[6];
    const float* H    = (const float*)d_in[7];
    const float* Win1 = (const float*)d_in[8];
    const float* Win2 = (const float*)d_in[9];
    float* out = (float*)d_out;
    float* ws  = (float*)d_ws;   // ws[0:256]=phi_xn, ws[256:768]=psi_z

    hipLaunchKernelGGL(k_state, dim3(18), dim3(256), 0, stream,
                       I, x, W, z, Win1, out, ws);
    // 1024 blocks x 512 thr: even = H(z) rows, odd = 128 D rows each (uniform 256 KB/block)
    hipLaunchKernelGGL(k_WZ, dim3(1024), dim3(512), 0, stream,
                       W, C, D, F, H, Win2, I, z, ws, out);
}